// Round 1
// baseline (799.666 us; speedup 1.0000x reference)
//
#include <hip/hip_runtime.h>
#include <math.h>

#define B_ 64
#define Q_ 50
#define N_ 32
#define E_ 64
#define D_ 128
#define H_ 4
#define EDIM_ 8
#define G_ (B_*Q_)

// XOR swizzle for [32][128] f32 LDS tiles: spreads row-column accesses across
// banks while keeping float4 alignment (flips word-index bits 2..4 only).
__device__ __forceinline__ int swz(int r, int d) { return (r << 7) + (d ^ ((r & 7) << 2)); }

// dst[row0..row0+3][colBase..colBase+3] = leaky(Xs[rows] @ W[:, cols] + b[cols], slope)
// Xs/dst are swizzled LDS [32][128]; W is global row-major with row stride wstride.
__device__ __forceinline__ void mm_tile(const float* Xs, const float* wp, int wstride,
                                        const float* bp, float slope,
                                        float* dst, int row0, int colBase)
{
  float acc[4][4] = {};
  for (int k0 = 0; k0 < D_; k0 += 4) {
    float4 x4[4], w4[4];
#pragma unroll
    for (int i = 0; i < 4; ++i) x4[i] = *(const float4*)&Xs[swz(row0 + i, k0)];
#pragma unroll
    for (int kk = 0; kk < 4; ++kk) w4[kk] = *(const float4*)&wp[(k0 + kk) * wstride];
#pragma unroll
    for (int i = 0; i < 4; ++i) {
      float xv[4] = {x4[i].x, x4[i].y, x4[i].z, x4[i].w};
#pragma unroll
      for (int kk = 0; kk < 4; ++kk) {
        acc[i][0] = fmaf(xv[kk], w4[kk].x, acc[i][0]);
        acc[i][1] = fmaf(xv[kk], w4[kk].y, acc[i][1]);
        acc[i][2] = fmaf(xv[kk], w4[kk].z, acc[i][2]);
        acc[i][3] = fmaf(xv[kk], w4[kk].w, acc[i][3]);
      }
    }
  }
  float4 b4 = *(const float4*)bp;
  float bb[4] = {b4.x, b4.y, b4.z, b4.w};
#pragma unroll
  for (int i = 0; i < 4; ++i) {
    float4 o; float v;
    v = acc[i][0] + bb[0]; o.x = v >= 0.f ? v : slope * v;
    v = acc[i][1] + bb[1]; o.y = v >= 0.f ? v : slope * v;
    v = acc[i][2] + bb[2]; o.z = v >= 0.f ? v : slope * v;
    v = acc[i][3] + bb[3]; o.w = v >= 0.f ? v : slope * v;
    *(float4*)&dst[swz(row0 + i, colBase)] = o;
  }
}

__global__ __launch_bounds__(256, 2)
void gat_fused(const float* __restrict__ qe, const int* __restrict__ qmask,
               const int* __restrict__ eidx, const int* __restrict__ ewt,
               const int* __restrict__ emsk,
               const float* __restrict__ ln1g, const float* __restrict__ ln1b,
               const float* __restrict__ embT,
               const float* __restrict__ Wl, const float* __restrict__ bl,
               const float* __restrict__ Wr, const float* __restrict__ br,
               const float* __restrict__ We, const float* __restrict__ att,
               const float* __restrict__ gatb,
               const float* __restrict__ W1, const float* __restrict__ b1,
               const float* __restrict__ W2, const float* __restrict__ b2,
               const float* __restrict__ ln2g, const float* __restrict__ ln2b,
               float* __restrict__ out)
{
  const int g = blockIdx.x;
  const int t = threadIdx.x;

  __shared__ float sX[N_ * D_];     // LN1(x), swizzled
  __shared__ float sXl[N_ * D_];    // per-head xl (reused as FFN h1)
  __shared__ float sXr[N_ * D_];    // per-head xr (reused as FFN h2)
  __shared__ float sAgg[N_ * D_];   // head-mean aggregate -> gout
  __shared__ float sWeh[EDIM_ * D_];
  __shared__ float sAtt[D_];
  __shared__ float sEembT[EDIM_][E_];
  __shared__ float sLoop[N_][EDIM_];
  __shared__ int   sSrc[E_], sDst[E_];
  __shared__ float sEm[E_];
  __shared__ float sExpE[E_];
  __shared__ float sLogit[E_];
  __shared__ float sLogitS[N_];
  __shared__ float sWs[N_];
  __shared__ float sNm[N_];
  __shared__ int   sDeg[N_], sStart[N_], sCur[N_];
  __shared__ int   sOrder[E_];
  __shared__ float sPool[D_];
  __shared__ float sValid, sNmSum;

  const int row0 = (t >> 5) << 2;      // 4-row tile
  const int colBase = (t & 31) << 2;   // 4-col tile

  // ---- Phase A: LN1 (8 lanes/row x 16 d) + edge/mask loads + zero agg ----
  {
    const int r = t >> 3;
    const int d0 = (t & 7) << 4;
    const float* src = qe + ((size_t)g * N_ + r) * D_ + d0;
    float v[16];
    float s = 0.f, ss = 0.f;
#pragma unroll
    for (int i = 0; i < 16; ++i) { float x = src[i]; v[i] = x; s += x; ss += x * x; }
#pragma unroll
    for (int m = 1; m < 8; m <<= 1) { s += __shfl_xor(s, m); ss += __shfl_xor(ss, m); }
    const float mu = s * (1.f / 128.f);
    const float inv = rsqrtf(ss * (1.f / 128.f) - mu * mu + 1e-5f);
#pragma unroll
    for (int i = 0; i < 16; ++i) {
      const int d = d0 + i;
      sX[swz(r, d)] = (v[i] - mu) * inv * ln1g[d] + ln1b[d];
    }
#pragma unroll
    for (int i = 0; i < 16; ++i) sAgg[(t << 4) + i] = 0.f;
    if (t < E_) {
      sSrc[t] = eidx[(size_t)g * 2 * E_ + t];
      sDst[t] = eidx[(size_t)g * 2 * E_ + E_ + t];
      sEm[t] = (float)emsk[(size_t)g * E_ + t];
      const int w = ewt[(size_t)g * E_ + t];
#pragma unroll
      for (int k = 0; k < EDIM_; ++k) sEembT[k][t] = embT[w * EDIM_ + k];
    } else if (t >= 64 && t < 96) {
      const int n = t - 64;
      sNm[n] = (float)qmask[(size_t)g * N_ + n];
    }
  }
  __syncthreads();

  // ---- Phase B: per-node degree, loop_attr (deterministic, no atomics) ----
  if (t < N_) {
    float cnt = 0.f; int dg = 0;
    float la[EDIM_] = {};
    for (int e = 0; e < E_; ++e) {
      if (sDst[e] == t) {
        ++dg;
        const float m = sEm[e];
        cnt += m;
#pragma unroll
        for (int k = 0; k < EDIM_; ++k) la[k] = fmaf(m, sEembT[k][e], la[k]);
      }
    }
    sDeg[t] = dg;
    const float rinv = 1.f / fmaxf(cnt, 1.f);
#pragma unroll
    for (int k = 0; k < EDIM_; ++k) sLoop[t][k] = la[k] * rinv;
  }
  __syncthreads();
  // CSR build (serial, deterministic) + valid flag
  if (t == 0) {
    int acc = 0;
    for (int n = 0; n < N_; ++n) { sStart[n] = acc; sCur[n] = acc; acc += sDeg[n]; }
    for (int e = 0; e < E_; ++e) { int dn = sDst[e]; sOrder[sCur[dn]++] = e; }
  } else if (t == 64) {
    float nms = 0.f;
    for (int n = 0; n < N_; ++n) nms += sNm[n];
    float ems = 0.f;
    for (int e = 0; e < E_; ++e) ems += sEm[e];
    sNmSum = nms;
    sValid = (nms > 0.f && ems > 0.f) ? 1.f : 0.f;
  }
  __syncthreads();

  // ---- Per-head GATv2 ----
  for (int h = 0; h < H_; ++h) {
    // E1: stage We[:, h*D:(h+1)*D] and att[h]
    {
      const int idx = t << 2;
      const int k = idx >> 7;
      const int d = idx & (D_ - 1);
      *(float4*)&sWeh[idx] = *(const float4*)&We[k * (H_ * D_) + h * D_ + d];
      if (t < 32) *(float4*)&sAtt[t << 2] = *(const float4*)&att[h * D_ + (t << 2)];
    }
    __syncthreads();
    // E2: xl = x@Wl_h + bl_h ; xr = x@Wr_h + br_h
    mm_tile(sX, Wl + h * D_ + colBase, H_ * D_, bl + h * D_ + colBase, 1.0f, sXl, row0, colBase);
    mm_tile(sX, Wr + h * D_ + colBase, H_ * D_, br + h * D_ + colBase, 1.0f, sXr, row0, colBase);
    __syncthreads();
    // E3: edge logits (4 lanes/edge, d interleaved stride 4)
    {
      const int e = t >> 2;
      const int qu = t & 3;
      const int sn = sSrc[e], dn = sDst[e];
      float ee[EDIM_];
#pragma unroll
      for (int k = 0; k < EDIM_; ++k) ee[k] = sEembT[k][e];
      float dot = 0.f;
#pragma unroll
      for (int i = 0; i < 32; ++i) {
        const int d = qu + (i << 2);
        float ev = 0.f;
#pragma unroll
        for (int k = 0; k < EDIM_; ++k) ev = fmaf(ee[k], sWeh[k * D_ + d], ev);
        float z = sXl[swz(sn, d)] + sXr[swz(dn, d)] + ev;
        z = z >= 0.f ? z : 0.2f * z;
        dot = fmaf(z, sAtt[d], dot);
      }
      dot += __shfl_xor(dot, 1);
      dot += __shfl_xor(dot, 2);
      if (qu == 0) sLogit[e] = (sEm[e] > 0.f) ? dot : -1e30f;
    }
    // E4: self-loop logits (8 lanes/node, d interleaved stride 8)
    {
      const int n = t >> 3;
      const int l8 = t & 7;
      float dot = 0.f;
#pragma unroll
      for (int i = 0; i < 16; ++i) {
        const int d = l8 + (i << 3);
        float lv = 0.f;
#pragma unroll
        for (int k = 0; k < EDIM_; ++k) lv = fmaf(sLoop[n][k], sWeh[k * D_ + d], lv);
        float z = sXl[swz(n, d)] + sXr[swz(n, d)] + lv;
        z = z >= 0.f ? z : 0.2f * z;
        dot = fmaf(z, sAtt[d], dot);
      }
      dot += __shfl_xor(dot, 1);
      dot += __shfl_xor(dot, 2);
      dot += __shfl_xor(dot, 4);
      if (l8 == 0) sLogitS[n] = dot;
    }
    __syncthreads();
    // E5: per-node segment softmax (deterministic serial over CSR)
    if (t < N_) {
      const int st = sStart[t], de = sDeg[t];
      float m = sLogitS[t];
      for (int j = 0; j < de; ++j) m = fmaxf(m, sLogit[sOrder[st + j]]);
      const float es = __expf(sLogitS[t] - m);
      float den = es;
      for (int j = 0; j < de; ++j) {
        const int e = sOrder[st + j];
        const float ex = (sEm[e] > 0.f) ? __expf(sLogit[e] - m) : 0.f;
        sExpE[e] = ex;
        den += ex;
      }
      const float rden = 1.f / den;
      sWs[t] = es * rden;
      for (int j = 0; j < de; ++j) sExpE[sOrder[st + j]] *= rden;
    }
    __syncthreads();
    // E6: weighted aggregation, accumulate head mean (x0.25)
    {
      const int n = t >> 3;
      const int l8 = t & 7;
      const int st = sStart[n], de = sDeg[n];
      float acc[16] = {};
      for (int j = 0; j < de; ++j) {
        const int e = sOrder[st + j];
        const float w = sExpE[e];
        const int sn = sSrc[e];
#pragma unroll
        for (int i = 0; i < 16; ++i) acc[i] = fmaf(w, sXl[swz(sn, l8 + (i << 3))], acc[i]);
      }
      const float ws = sWs[n];
#pragma unroll
      for (int i = 0; i < 16; ++i) {
        const int d = l8 + (i << 3);
        sAgg[swz(n, d)] += 0.25f * fmaf(ws, sXl[swz(n, d)], acc[i]);
      }
    }
    __syncthreads();
  }

  // ---- gout = mean-head agg + gat_b ----
  {
    const int n = t >> 3;
    const int l8 = t & 7;
#pragma unroll
    for (int i = 0; i < 16; ++i) {
      const int d = l8 + (i << 3);
      sAgg[swz(n, d)] += gatb[d];
    }
  }
  __syncthreads();
  // ---- FFN ----
  mm_tile(sAgg, W1 + colBase, D_, b1 + colBase, 0.01f, sXl, row0, colBase);
  __syncthreads();
  mm_tile(sXl, W2 + colBase, D_, b2 + colBase, 1.0f, sXr, row0, colBase);
  __syncthreads();
  // ---- masked mean pool ----
  if (t < D_) {
    float acc = 0.f;
    for (int n = 0; n < N_; ++n) acc = fmaf(sXr[swz(n, t)], sNm[n], acc);
    sPool[t] = acc * (1.f / fmaxf(sNmSum, 1.f)) * sValid;
  }
  __syncthreads();
  // ---- LN2 + store (wave 0, 2 d's per lane) ----
  if (t < 64) {
    const float v0 = sPool[t], v1 = sPool[t + 64];
    float s = v0 + v1, ss = v0 * v0 + v1 * v1;
#pragma unroll
    for (int m = 1; m < 64; m <<= 1) { s += __shfl_xor(s, m); ss += __shfl_xor(ss, m); }
    const float mu = s * (1.f / 128.f);
    const float inv = rsqrtf(ss * (1.f / 128.f) - mu * mu + 1e-5f);
    float* op = out + (size_t)g * D_;
    op[t] = (v0 - mu) * inv * ln2g[t] + ln2b[t];
    op[t + 64] = (v1 - mu) * inv * ln2g[t + 64] + ln2b[t + 64];
  }
}

extern "C" void kernel_launch(void* const* d_in, const int* in_sizes, int n_in,
                              void* d_out, int out_size, void* d_ws, size_t ws_size,
                              hipStream_t stream) {
  (void)in_sizes; (void)n_in; (void)out_size; (void)d_ws; (void)ws_size;
  const float* qe   = (const float*)d_in[0];
  const int*   qm   = (const int*)d_in[1];
  const int*   ei   = (const int*)d_in[2];
  const int*   ew   = (const int*)d_in[3];
  const int*   em   = (const int*)d_in[4];
  const float* ln1g = (const float*)d_in[5];
  const float* ln1b = (const float*)d_in[6];
  const float* embT = (const float*)d_in[7];
  const float* Wl   = (const float*)d_in[8];
  const float* bl   = (const float*)d_in[9];
  const float* Wr   = (const float*)d_in[10];
  const float* br   = (const float*)d_in[11];
  const float* We   = (const float*)d_in[12];
  const float* att  = (const float*)d_in[13];
  const float* gatb = (const float*)d_in[14];
  const float* W1   = (const float*)d_in[15];
  const float* b1   = (const float*)d_in[16];
  const float* W2   = (const float*)d_in[17];
  const float* b2   = (const float*)d_in[18];
  const float* ln2g = (const float*)d_in[19];
  const float* ln2b = (const float*)d_in[20];
  float* out = (float*)d_out;

  gat_fused<<<dim3(G_), dim3(256), 0, stream>>>(
      qe, qm, ei, ew, em, ln1g, ln1b, embT, Wl, bl, Wr, br, We, att, gatb,
      W1, b1, W2, b2, ln2g, ln2b, out);
}

// Round 2
// 430.016 us; speedup vs baseline: 1.8596x; 1.8596x over previous
//
#include <hip/hip_runtime.h>
#include <math.h>

#define B_ 64
#define Q_ 50
#define N_ 32
#define E_ 64
#define D_ 128
#define H_ 4
#define EDIM_ 8
#define G_ (B_*Q_)

// d_ws layout (bytes)
#define WLP_OFF 0          // 4h x 4q x 128n x 32kk bf16 = 131072 B
#define WRP_OFF 131072
#define W1P_OFF 262144     // 4q x 128n x 32kk bf16 = 32768 B
#define W2P_OFF 294912
#define EW_OFF  327680     // 2 x 512 f32 = 4096 B
#define XA_OFF  331776     // G x 4096 bf16 (A-fragment packed) = 26214400 B

typedef __attribute__((ext_vector_type(8))) short short8;
typedef __attribute__((ext_vector_type(4))) float f32x4;

// XOR swizzle for [32][128] f32 LDS tiles (flips word-index bits 2..4).
__device__ __forceinline__ int swz(int r, int d) { return (r << 7) + (d ^ ((r & 7) << 2)); }

__device__ __forceinline__ unsigned short f2b(float f) {
  unsigned u = __float_as_uint(f);
  u += 0x7fffu + ((u >> 16) & 1u);
  return (unsigned short)(u >> 16);
}

// ---------------- prep kernel A: pack weights + EW table ----------------
__global__ __launch_bounds__(256)
void pack_weights(const float* __restrict__ Wl, const float* __restrict__ Wr,
                  const float* __restrict__ W1, const float* __restrict__ W2,
                  const float* __restrict__ embT, const float* __restrict__ We,
                  unsigned char* __restrict__ ws)
{
  const int i = blockIdx.x * 256 + threadIdx.x;
  unsigned short* wlp = (unsigned short*)(ws + WLP_OFF);
  unsigned short* wrp = (unsigned short*)(ws + WRP_OFF);
  unsigned short* w1p = (unsigned short*)(ws + W1P_OFF);
  unsigned short* w2p = (unsigned short*)(ws + W2P_OFF);
  float* ew = (float*)(ws + EW_OFF);
  if (i < 65536) {
    // B-packed: idx = ((h*4+q)*128 + n)*32 + kk  <=  W[(q*32+kk)][h*128+n]
    const int kk = i & 31, n = (i >> 5) & 127, q = (i >> 12) & 3, h = i >> 14;
    wlp[i] = f2b(Wl[(q * 32 + kk) * (H_ * D_) + h * D_ + n]);
    wrp[i] = f2b(Wr[(q * 32 + kk) * (H_ * D_) + h * D_ + n]);
  } else if (i < 65536 + 16384) {
    const int j = i - 65536;
    const int kk = j & 31, n = (j >> 5) & 127, q = j >> 12;
    w1p[j] = f2b(W1[(q * 32 + kk) * D_ + n]);
    w2p[j] = f2b(W2[(q * 32 + kk) * D_ + n]);
  } else if (i < 65536 + 16384 + 1024) {
    const int j = i - 65536 - 16384;
    const int w = j >> 9, hd = j & 511;
    float a = 0.f;
#pragma unroll
    for (int k = 0; k < EDIM_; ++k) a = fmaf(embT[w * EDIM_ + k], We[k * (H_ * D_) + hd], a);
    ew[j] = a;
  }
}

// ---------------- prep kernel B: LN1 + pack to A-fragment bf16 ----------------
__global__ __launch_bounds__(256)
void ln_pack(const float* __restrict__ qe, const float* __restrict__ ln1g,
             const float* __restrict__ ln1b, unsigned char* __restrict__ ws)
{
  const int g = blockIdx.x, t = threadIdx.x;
  const int r = t >> 3, d0 = (t & 7) << 4;
  const float* src = qe + ((size_t)g * N_ + r) * D_ + d0;
  float v[16];
  float s = 0.f, ss = 0.f;
#pragma unroll
  for (int i = 0; i < 16; ++i) { float x = src[i]; v[i] = x; s += x; ss += x * x; }
#pragma unroll
  for (int m = 1; m < 8; m <<= 1) { s += __shfl_xor(s, m); ss += __shfl_xor(ss, m); }
  const float mu = s * (1.f / 128.f);
  const float inv = rsqrtf(ss * (1.f / 128.f) - mu * mu + 1e-5f);
  unsigned short o[16] __attribute__((aligned(16)));
#pragma unroll
  for (int i = 0; i < 16; ++i)
    o[i] = f2b((v[i] - mu) * inv * ln1g[d0 + i] + ln1b[d0 + i]);
  unsigned short* xa = (unsigned short*)(ws + XA_OFF) + (size_t)g * 4096;
  const int c = r >> 4;
#pragma unroll
  for (int p = 0; p < 2; ++p) {
    const int k8 = d0 + p * 8;
    const int q = k8 >> 5, lhi = (k8 >> 3) & 3;
    const int idx = ((c * 4 + q) * 64 + (lhi * 16 + (r & 15))) * 8;
    *(float4*)&xa[idx] = *(const float4*)&o[p * 8];
  }
}

// ---------------- MFMA GEMM: [32 x 128] = A[32x128] @ Bpacked[128x128] ----------------
// Each wave: n-quarter nq (32 cols), both m-tiles. Out: f32 swizzled LDS + bias + leaky.
__device__ __forceinline__ void gemm_e(const short8 aF[2][4], const unsigned short* __restrict__ Bp,
                                       const float* __restrict__ bias, float slope,
                                       float* __restrict__ dst, int lane, int nq)
{
#pragma unroll
  for (int nt = 0; nt < 2; ++nt) {
    const int col = nq * 32 + nt * 16 + (lane & 15);
    f32x4 acc0 = {0.f, 0.f, 0.f, 0.f}, acc1 = {0.f, 0.f, 0.f, 0.f};
#pragma unroll
    for (int q = 0; q < 4; ++q) {
      const short8 b = *(const short8*)&Bp[((q << 7) + col) * 32 + ((lane >> 4) << 3)];
      acc0 = __builtin_amdgcn_mfma_f32_16x16x32_bf16(aF[0][q], b, acc0, 0, 0, 0);
      acc1 = __builtin_amdgcn_mfma_f32_16x16x32_bf16(aF[1][q], b, acc1, 0, 0, 0);
    }
    const float bb = bias[col];
    const int r0 = (lane >> 4) << 2;
#pragma unroll
    for (int r = 0; r < 4; ++r) {
      float v0 = acc0[r] + bb; v0 = v0 >= 0.f ? v0 : slope * v0;
      float v1 = acc1[r] + bb; v1 = v1 >= 0.f ? v1 : slope * v1;
      dst[swz(r0 + r, col)] = v0;
      dst[swz(16 + r0 + r, col)] = v1;
    }
  }
}

// convert f32 swizzled LDS tile -> A fragment (bf16)
__device__ __forceinline__ short8 cvt_frag(const float* __restrict__ S, int c, int q, int lane)
{
  const int m = c * 16 + (lane & 15);
  const int k0 = q * 32 + ((lane >> 4) << 3);
  const float4 x0 = *(const float4*)&S[swz(m, k0)];
  const float4 x1 = *(const float4*)&S[swz(m, k0 + 4)];
  const float v[8] = {x0.x, x0.y, x0.z, x0.w, x1.x, x1.y, x1.z, x1.w};
  short8 r;
#pragma unroll
  for (int j = 0; j < 8; ++j) r[j] = (short)f2b(v[j]);
  return r;
}

// ---------------- main fused kernel: one block per group ----------------
__global__ __launch_bounds__(256, 3)
void gat_main(const unsigned char* __restrict__ ws,
              const int* __restrict__ qmask, const int* __restrict__ eidx,
              const int* __restrict__ ewt, const int* __restrict__ emsk,
              const float* __restrict__ bl, const float* __restrict__ br,
              const float* __restrict__ att, const float* __restrict__ gatb,
              const float* __restrict__ b1, const float* __restrict__ b2,
              const float* __restrict__ ln2g, const float* __restrict__ ln2b,
              float* __restrict__ out)
{
  const int g = blockIdx.x, t = threadIdx.x;
  const int lane = t & 63, wave = t >> 6;

  __shared__ float sXl[N_ * D_], sXr[N_ * D_], sAgg[N_ * D_];
  __shared__ float sEW[2][D_];
  __shared__ float sAtt[D_];
  __shared__ int sSrc[E_], sDst[E_], sWt[E_];
  __shared__ float sEm[E_], sExpE[E_], sLogit[E_];
  __shared__ float sLogitS[N_], sWs[N_], sNm[N_], sC0[N_], sC1[N_];
  __shared__ int sDeg[N_], sStart[N_], sCur[N_], sOrder[E_];
  __shared__ float sPool[D_];
  __shared__ float sValid, sNmSum;

  // A fragments for this lane (reused for all 8 E2 GEMMs)
  short8 aF[2][4];
  {
    const short8* xa = (const short8*)(ws + XA_OFF) + (size_t)g * 512;
#pragma unroll
    for (int c = 0; c < 2; ++c)
#pragma unroll
      for (int q = 0; q < 4; ++q)
        aF[c][q] = xa[(c * 4 + q) * 64 + lane];
  }

#pragma unroll
  for (int i = 0; i < 16; ++i) sAgg[(t << 4) + i] = 0.f;
  if (t < E_) {
    sSrc[t] = eidx[(size_t)g * 2 * E_ + t];
    sDst[t] = eidx[(size_t)g * 2 * E_ + E_ + t];
    sWt[t] = ewt[(size_t)g * E_ + t];
    sEm[t] = (float)emsk[(size_t)g * E_ + t];
  } else if (t >= 64 && t < 96) {
    sNm[t - 64] = (float)qmask[(size_t)g * N_ + (t - 64)];
  }
  __syncthreads();

  // per-node degree + edge-weight-class coefficients (loop_attr via EW linearity)
  if (t < N_) {
    float cnt = 0.f; int dg = 0; float c0 = 0.f, c1 = 0.f;
    for (int e = 0; e < E_; ++e) {
      if (sDst[e] == t) {
        ++dg;
        const float m = sEm[e];
        cnt += m;
        if (sWt[e] == 0) c0 += m; else c1 += m;
      }
    }
    sDeg[t] = dg;
    const float rinv = 1.f / fmaxf(cnt, 1.f);
    sC0[t] = c0 * rinv; sC1[t] = c1 * rinv;
  }
  __syncthreads();
  if (t == 0) {
    int acc = 0;
    for (int n = 0; n < N_; ++n) { sStart[n] = acc; sCur[n] = acc; acc += sDeg[n]; }
    for (int e = 0; e < E_; ++e) { int dn = sDst[e]; sOrder[sCur[dn]++] = e; }
  } else if (t == 64) {
    float nms = 0.f; for (int n = 0; n < N_; ++n) nms += sNm[n];
    float ems = 0.f; for (int e = 0; e < E_; ++e) ems += sEm[e];
    sNmSum = nms;
    sValid = (nms > 0.f && ems > 0.f) ? 1.f : 0.f;
  }
  __syncthreads();

  const unsigned short* wlp = (const unsigned short*)(ws + WLP_OFF);
  const unsigned short* wrp = (const unsigned short*)(ws + WRP_OFF);
  const float* ew = (const float*)(ws + EW_OFF);

  for (int h = 0; h < H_; ++h) {
    // stage per-head tables (no dependency on GEMM output)
    sEW[t >> 7][t & 127] = ew[(t >> 7) * (H_ * D_) + h * D_ + (t & 127)];
    if (t < 32) *(float4*)&sAtt[t << 2] = *(const float4*)&att[h * D_ + (t << 2)];
    // E2: xl / xr projections via MFMA
    gemm_e(aF, wlp + h * 16384, bl + h * D_, 1.0f, sXl, lane, wave);
    gemm_e(aF, wrp + h * 16384, br + h * D_, 1.0f, sXr, lane, wave);
    __syncthreads();
    // E3: edge logits (4 lanes/edge)
    {
      const int e = t >> 2, qu = t & 3;
      const int sn = sSrc[e], dn = sDst[e];
      const float* ewr = sEW[sWt[e]];
      float dot = 0.f;
#pragma unroll
      for (int i = 0; i < 32; ++i) {
        const int d = qu + (i << 2);
        float z = sXl[swz(sn, d)] + sXr[swz(dn, d)] + ewr[d];
        z = z >= 0.f ? z : 0.2f * z;
        dot = fmaf(z, sAtt[d], dot);
      }
      dot += __shfl_xor(dot, 1);
      dot += __shfl_xor(dot, 2);
      if (qu == 0) sLogit[e] = (sEm[e] > 0.f) ? dot : -1e30f;
    }
    // E4: self-loop logits (8 lanes/node)
    {
      const int n = t >> 3, l8 = t & 7;
      const float c0 = sC0[n], c1 = sC1[n];
      float dot = 0.f;
#pragma unroll
      for (int i = 0; i < 16; ++i) {
        const int d = l8 + (i << 3);
        float z = sXl[swz(n, d)] + sXr[swz(n, d)] + c0 * sEW[0][d] + c1 * sEW[1][d];
        z = z >= 0.f ? z : 0.2f * z;
        dot = fmaf(z, sAtt[d], dot);
      }
      dot += __shfl_xor(dot, 1);
      dot += __shfl_xor(dot, 2);
      dot += __shfl_xor(dot, 4);
      if (l8 == 0) sLogitS[n] = dot;
    }
    __syncthreads();
    // E5: deterministic per-node segment softmax
    if (t < N_) {
      const int st = sStart[t], de = sDeg[t];
      float m = sLogitS[t];
      for (int j = 0; j < de; ++j) m = fmaxf(m, sLogit[sOrder[st + j]]);
      const float es = __expf(sLogitS[t] - m);
      float den = es;
      for (int j = 0; j < de; ++j) {
        const int e = sOrder[st + j];
        const float ex = (sEm[e] > 0.f) ? __expf(sLogit[e] - m) : 0.f;
        sExpE[e] = ex;
        den += ex;
      }
      const float rden = 1.f / den;
      sWs[t] = es * rden;
      for (int j = 0; j < de; ++j) sExpE[sOrder[st + j]] *= rden;
    }
    __syncthreads();
    // E6: weighted aggregation, accumulate head mean
    {
      const int n = t >> 3, l8 = t & 7;
      const int st = sStart[n], de = sDeg[n];
      float acc[16] = {};
      for (int j = 0; j < de; ++j) {
        const int e = sOrder[st + j];
        const float w = sExpE[e];
        const int sn = sSrc[e];
#pragma unroll
        for (int i = 0; i < 16; ++i) acc[i] = fmaf(w, sXl[swz(sn, l8 + (i << 3))], acc[i]);
      }
      const float wsf = sWs[n];
#pragma unroll
      for (int i = 0; i < 16; ++i) {
        const int d = l8 + (i << 3);
        sAgg[swz(n, d)] += 0.25f * fmaf(wsf, sXl[swz(n, d)], acc[i]);
      }
    }
    __syncthreads();
  }

  // gout = agg + gat_b  (stage gatb via sAtt)
  if (t < 32) *(float4*)&sAtt[t << 2] = *(const float4*)&gatb[t << 2];
  __syncthreads();
  {
    const int n = t >> 3, l8 = t & 7;
#pragma unroll
    for (int i = 0; i < 16; ++i) {
      const int d = l8 + (i << 3);
      sAgg[swz(n, d)] += sAtt[d];
    }
  }
  __syncthreads();

  // FFN via MFMA
  {
    short8 aG[2][4];
#pragma unroll
    for (int c = 0; c < 2; ++c)
#pragma unroll
      for (int q = 0; q < 4; ++q) aG[c][q] = cvt_frag(sAgg, c, q, lane);
    gemm_e(aG, (const unsigned short*)(ws + W1P_OFF), b1, 0.01f, sXl, lane, wave);
    __syncthreads();
#pragma unroll
    for (int c = 0; c < 2; ++c)
#pragma unroll
      for (int q = 0; q < 4; ++q) aG[c][q] = cvt_frag(sXl, c, q, lane);
    gemm_e(aG, (const unsigned short*)(ws + W2P_OFF), b2, 1.0f, sXr, lane, wave);
  }
  __syncthreads();

  // masked mean pool
  if (t < D_) {
    float acc = 0.f;
    for (int n = 0; n < N_; ++n) acc = fmaf(sXr[swz(n, t)], sNm[n], acc);
    sPool[t] = acc * (1.f / fmaxf(sNmSum, 1.f)) * sValid;
  }
  __syncthreads();
  // LN2 + store
  if (t < 64) {
    const float v0 = sPool[t], v1 = sPool[t + 64];
    float s = v0 + v1, ss = v0 * v0 + v1 * v1;
#pragma unroll
    for (int m = 1; m < 64; m <<= 1) { s += __shfl_xor(s, m); ss += __shfl_xor(ss, m); }
    const float mu = s * (1.f / 128.f);
    const float inv = rsqrtf(ss * (1.f / 128.f) - mu * mu + 1e-5f);
    float* op = out + (size_t)g * D_;
    op[t] = (v0 - mu) * inv * ln2g[t] + ln2b[t];
    op[t + 64] = (v1 - mu) * inv * ln2g[t + 64] + ln2b[t + 64];
  }
}

extern "C" void kernel_launch(void* const* d_in, const int* in_sizes, int n_in,
                              void* d_out, int out_size, void* d_ws, size_t ws_size,
                              hipStream_t stream) {
  (void)in_sizes; (void)n_in; (void)out_size; (void)ws_size;
  const float* qe   = (const float*)d_in[0];
  const int*   qm   = (const int*)d_in[1];
  const int*   ei   = (const int*)d_in[2];
  const int*   ew   = (const int*)d_in[3];
  const int*   em   = (const int*)d_in[4];
  const float* ln1g = (const float*)d_in[5];
  const float* ln1b = (const float*)d_in[6];
  const float* embT = (const float*)d_in[7];
  const float* Wl   = (const float*)d_in[8];
  const float* bl   = (const float*)d_in[9];
  const float* Wr   = (const float*)d_in[10];
  const float* br   = (const float*)d_in[11];
  const float* We   = (const float*)d_in[12];
  const float* att  = (const float*)d_in[13];
  const float* gatb = (const float*)d_in[14];
  const float* W1   = (const float*)d_in[15];
  const float* b1   = (const float*)d_in[16];
  const float* W2   = (const float*)d_in[17];
  const float* b2   = (const float*)d_in[18];
  const float* ln2g = (const float*)d_in[19];
  const float* ln2b = (const float*)d_in[20];
  float* out = (float*)d_out;
  unsigned char* ws = (unsigned char*)d_ws;

  pack_weights<<<dim3(324), dim3(256), 0, stream>>>(Wl, Wr, W1, W2, embT, We, ws);
  ln_pack<<<dim3(G_), dim3(256), 0, stream>>>(qe, ln1g, ln1b, ws);
  gat_main<<<dim3(G_), dim3(256), 0, stream>>>(ws, qm, ei, ew, em, bl, br, att, gatb,
                                               b1, b2, ln2g, ln2b, out);
}